// Round 7
// baseline (7259.888 us; speedup 1.0000x reference)
//
#include <hip/hip_runtime.h>
#include <math.h>

#define NN 100000
#define NE 3200000
#define NG 1024
#define FDIM 128
#define NFC1 64
#define NFC2 10

#define NGROUPS 1563   // ceil(NN/64) dst groups of 64 nodes
#define CAP2 2432      // per-group staging cap (mean 2048, +8.5 sigma)
#define EPB 16         // edges per thread in bin2_kernel
#define CSHIFT 11      // src chunk = src>>11 (2048 rows = 1 MB fp32 per chunk)
#define NCH 49         // ceil(100000/2048)

#define RF(x) __builtin_amdgcn_readfirstlane(x)

// ---------------- pass 1: bin edges into 1563 dst-groups ----------------
// Packed value: (dst & 63) << 17 | src   (src < 2^17, dst_local < 2^6)
__global__ __launch_bounds__(256) void bin2_kernel(const int* __restrict__ src,
                                                   const int* __restrict__ dst,
                                                   int* __restrict__ gcount,
                                                   int* __restrict__ staging) {
  __shared__ int hist[NGROUPS];
  __shared__ int base[NGROUPS];
  int t = threadIdx.x;
  for (int i = t; i < NGROUPS; i += 256) hist[i] = 0;
  __syncthreads();
  size_t e0 = (size_t)blockIdx.x * (256 * EPB);
  int bk[EPB], rank[EPB], val[EPB];
#pragma unroll
  for (int j = 0; j < EPB; ++j) {
    size_t e = e0 + (size_t)j * 256 + t;
    if (e < NE) {
      int d = dst[e];
      bk[j] = d >> 6;
      val[j] = ((d & 63) << 17) | src[e];
      rank[j] = atomicAdd(&hist[bk[j]], 1);
    } else {
      bk[j] = -1;
    }
  }
  __syncthreads();
  for (int i = t; i < NGROUPS; i += 256) {
    int h = hist[i];
    base[i] = h > 0 ? atomicAdd(&gcount[i], h) : 0;
  }
  __syncthreads();
#pragma unroll
  for (int j = 0; j < EPB; ++j) {
    if (bk[j] >= 0) {
      int pos = base[bk[j]] + rank[j];
      if (pos < CAP2) staging[(size_t)bk[j] * CAP2 + pos] = val[j];
    }
  }
}

// ---------------- pass 1.5: exclusive scan of group counts ----------------
__global__ __launch_bounds__(256) void scan_groups(const int* __restrict__ gcount,
                                                   int* __restrict__ gbase) {
  __shared__ int s[256];
  __shared__ int carry;
  int t = threadIdx.x;
  if (t == 0) carry = 0;
  __syncthreads();
  for (int tile = 0; tile < (NGROUPS + 255) / 256; ++tile) {
    int i = tile * 256 + t;
    int v = (i < NGROUPS) ? gcount[i] : 0;
    s[t] = v;
    __syncthreads();
    for (int st = 1; st < 256; st <<= 1) {
      int u = (t >= st) ? s[t - st] : 0;
      __syncthreads();
      s[t] += u;
      __syncthreads();
    }
    int c0 = carry;
    if (i < NGROUPS) gbase[i] = c0 + s[t] - v;
    __syncthreads();
    if (t == 255) carry = c0 + s[255];
    __syncthreads();
  }
  if (t == 0) gbase[NGROUPS] = carry;
}

// ---------------- pass 2: per-group sort by src-chunk ----------------
// Sorting each group's edges by src>>11 makes every block sweep src in
// ascending order during aggregation -> all resident blocks gather from a
// narrow moving src window that fits per-XCD L2.
__global__ __launch_bounds__(256) void finalize_kernel(const int* __restrict__ staging,
                                                       const int* __restrict__ gcount,
                                                       const int* __restrict__ gbase,
                                                       int* __restrict__ esrc2) {
  __shared__ int vals[CAP2];
  __shared__ int sorted[CAP2];
  __shared__ int hist[NCH + 1];
  __shared__ int cur[NCH];
  int g = blockIdx.x, t = threadIdx.x;
  int cnt = gcount[g];
  if (cnt > CAP2) cnt = CAP2;
  int base = gbase[g];
  for (int i = t; i <= NCH; i += 256) hist[i] = 0;
  __syncthreads();
  const int* sp = staging + (size_t)g * CAP2;
  for (int i = t; i < cnt; i += 256) {
    int v = sp[i];
    vals[i] = v;
    atomicAdd(&hist[((v & 0x1FFFF) >> CSHIFT) + 1], 1);
  }
  __syncthreads();
  if (t == 0) {
    for (int c = 1; c <= NCH; ++c) hist[c] += hist[c - 1];
  }
  __syncthreads();
  for (int i = t; i < NCH; i += 256) cur[i] = hist[i];
  __syncthreads();
  for (int i = t; i < cnt; i += 256) {
    int v = vals[i];
    int c = (v & 0x1FFFF) >> CSHIFT;
    int pos = atomicAdd(&cur[c], 1);
    sorted[pos] = v;
  }
  __syncthreads();
  for (int i = t; i < cnt; i += 256) esrc2[base + i] = sorted[i];
}

// ---------------- fused conv layer: out = relu(gather(x)@W + bias) ----------------
// One block (256 thr = 4 waves) per 64-node dst group.
// Phase 1: LDS acc[64][128] zeroed; waves process the group's src-sorted edge
//   list interleaved (e = base + w + 4i) so all waves sweep src together.
//   Per edge: lane reads features {lane, lane+64} of the src row (2 x 256B
//   coalesced loads) and LDS-atomicAdds into acc row dst_local (bank-conflict
//   free: 2 lanes/bank).
// Phase 2: 64x128 tile GEMM from acc (broadcast b128 reads) with W from L1.
__global__ __launch_bounds__(256) void conv_g(const float* __restrict__ x,
                                              const int* __restrict__ gbase,
                                              const int* __restrict__ esrc2,
                                              const float* __restrict__ W,
                                              const float* __restrict__ bias,
                                              float* __restrict__ out) {
  __shared__ __align__(16) float acc[64 * 128];
  int t = threadIdx.x;
  int w = t >> 6;
  int lane = t & 63;
  int g = blockIdx.x;
  for (int i = t; i < 2048; i += 256) ((float4*)acc)[i] = make_float4(0.f, 0.f, 0.f, 0.f);
  int base = gbase[g], end = gbase[g + 1];
  __syncthreads();

  // ---- phase 1: gather + LDS accumulate ----
  int e = base + w;
  for (; e + 12 < end; e += 16) {
    int v0 = RF(esrc2[e]);
    int v1 = RF(esrc2[e + 4]);
    int v2 = RF(esrc2[e + 8]);
    int v3 = RF(esrc2[e + 12]);
    int r0 = v0 & 0x1FFFF, d0 = v0 >> 17;
    int r1 = v1 & 0x1FFFF, d1 = v1 >> 17;
    int r2 = v2 & 0x1FFFF, d2 = v2 >> 17;
    int r3 = v3 & 0x1FFFF, d3 = v3 >> 17;
    float a00 = x[(size_t)r0 * 128 + lane], a01 = x[(size_t)r0 * 128 + 64 + lane];
    float a10 = x[(size_t)r1 * 128 + lane], a11 = x[(size_t)r1 * 128 + 64 + lane];
    float a20 = x[(size_t)r2 * 128 + lane], a21 = x[(size_t)r2 * 128 + 64 + lane];
    float a30 = x[(size_t)r3 * 128 + lane], a31 = x[(size_t)r3 * 128 + 64 + lane];
    atomicAdd(&acc[d0 * 128 + lane], a00);
    atomicAdd(&acc[d0 * 128 + 64 + lane], a01);
    atomicAdd(&acc[d1 * 128 + lane], a10);
    atomicAdd(&acc[d1 * 128 + 64 + lane], a11);
    atomicAdd(&acc[d2 * 128 + lane], a20);
    atomicAdd(&acc[d2 * 128 + 64 + lane], a21);
    atomicAdd(&acc[d3 * 128 + lane], a30);
    atomicAdd(&acc[d3 * 128 + 64 + lane], a31);
  }
  for (; e < end; e += 4) {
    int v = RF(esrc2[e]);
    int r = v & 0x1FFFF, d = v >> 17;
    atomicAdd(&acc[d * 128 + lane], x[(size_t)r * 128 + lane]);
    atomicAdd(&acc[d * 128 + 64 + lane], x[(size_t)r * 128 + 64 + lane]);
  }
  __syncthreads();

  // ---- phase 2: GEMM 64x128 tile ----
  int rg = lane >> 5;
  int c = lane & 31;
  int rbase = w * 16 + rg * 8;

  float s[8][4];
#pragma unroll
  for (int r = 0; r < 8; ++r)
#pragma unroll
    for (int j = 0; j < 4; ++j) s[r][j] = 0.f;

#pragma unroll 2
  for (int k = 0; k < 128; k += 4) {
    float4 b0 = *(const float4*)(W + (k + 0) * FDIM + c * 4);
    float4 b1 = *(const float4*)(W + (k + 1) * FDIM + c * 4);
    float4 b2 = *(const float4*)(W + (k + 2) * FDIM + c * 4);
    float4 b3 = *(const float4*)(W + (k + 3) * FDIM + c * 4);
#pragma unroll
    for (int r = 0; r < 8; ++r) {
      float4 a = *(const float4*)&acc[(rbase + r) * 128 + k];
      s[r][0] += a.x * b0.x + a.y * b1.x + a.z * b2.x + a.w * b3.x;
      s[r][1] += a.x * b0.y + a.y * b1.y + a.z * b2.y + a.w * b3.y;
      s[r][2] += a.x * b0.z + a.y * b1.z + a.z * b2.z + a.w * b3.z;
      s[r][3] += a.x * b0.w + a.y * b1.w + a.z * b2.w + a.w * b3.w;
    }
  }

  float4 bb = *(const float4*)(bias + c * 4);
#pragma unroll
  for (int r = 0; r < 8; ++r) {
    int row = g * 64 + rbase + r;
    if (row < NN) {
      float4 o;
      o.x = fmaxf(s[r][0] + bb.x, 0.f);
      o.y = fmaxf(s[r][1] + bb.y, 0.f);
      o.z = fmaxf(s[r][2] + bb.z, 0.f);
      o.w = fmaxf(s[r][3] + bb.w, 0.f);
      *(float4*)(out + (size_t)row * FDIM + c * 4) = o;
    }
  }
}

// ---------------- fused global pool + FC1 + FC2 + softmax ----------------
__device__ int lower_bound_dev(const int* __restrict__ arr, int n, int val) {
  int lo = 0, hi = n;
  while (lo < hi) {
    int mid = (lo + hi) >> 1;
    if (arr[mid] < val) lo = mid + 1; else hi = mid;
  }
  return lo;
}

__global__ __launch_bounds__(128) void pool_head(const float* __restrict__ x,
                                                 const int* __restrict__ batching,
                                                 const float* __restrict__ Wf1,
                                                 const float* __restrict__ bf1,
                                                 const float* __restrict__ Wf2,
                                                 const float* __restrict__ bf2,
                                                 float* __restrict__ out) {
  __shared__ int se, ee;
  __shared__ float gl[128];
  __shared__ float hl[64];
  __shared__ float ol[10];
  __shared__ float red[2];
  int gid = blockIdx.x, t = threadIdx.x;
  if (t == 0) {
    se = lower_bound_dev(batching, NN, gid);
    ee = lower_bound_dev(batching, NN, gid + 1);
  }
  __syncthreads();
  float acc = 0.f;
  for (int n = se; n < ee; ++n) acc += x[(size_t)n * FDIM + t];
  gl[t] = acc;
  __syncthreads();
  if (t < NFC1) {
    float h = bf1[t];
    for (int f = 0; f < 128; ++f) h += gl[f] * Wf1[f * NFC1 + t];
    hl[t] = h;
  }
  __syncthreads();
  if (t < NFC2) {
    float o = bf2[t];
    for (int i = 0; i < NFC1; ++i) o += hl[i] * Wf2[i * NFC2 + t];
    ol[t] = o;
  }
  __syncthreads();
  if (t == 0) {
    float m = ol[0];
    for (int i = 1; i < NFC2; ++i) m = fmaxf(m, ol[i]);
    float sum = 0.f;
    for (int i = 0; i < NFC2; ++i) sum += expf(ol[i] - m);
    red[0] = m;
    red[1] = sum;
  }
  __syncthreads();
  if (t < NFC2) out[(size_t)gid * NFC2 + t] = expf(ol[t] - red[0]) / red[1];
}

extern "C" void kernel_launch(void* const* d_in, const int* in_sizes, int n_in,
                              void* d_out, int out_size, void* d_ws, size_t ws_size,
                              hipStream_t stream) {
  const float* node_attr = (const float*)d_in[0];
  const float* Wc = (const float*)d_in[1];   // [3][128][128]
  const float* bc = (const float*)d_in[2];   // [3][128]
  const float* Wf1 = (const float*)d_in[3];  // [128][64]
  const float* bf1 = (const float*)d_in[4];
  const float* Wf2 = (const float*)d_in[5];  // [64][10]
  const float* bf2 = (const float*)d_in[6];
  const int* src = (const int*)d_in[7];
  const int* dst = (const int*)d_in[8];
  const int* batching = (const int*)d_in[9];
  float* out = (float*)d_out;

  char* wsp = (char*)d_ws;
  size_t off = 0;
  auto alloc = [&](size_t bytes) -> void* {
    void* p = wsp + off;
    off += (bytes + 255) & ~(size_t)255;
    return p;
  };
  int* gcount = (int*)alloc((size_t)NGROUPS * sizeof(int));
  int* gbase = (int*)alloc((size_t)(NGROUPS + 1) * sizeof(int));
  int* esrc2 = (int*)alloc((size_t)NE * sizeof(int));
  float* bufA = (float*)alloc((size_t)NN * FDIM * sizeof(float));
  float* bufB = (float*)alloc((size_t)NN * FDIM * sizeof(float));
  // staging (15.2 MB) aliases bufB (51.2 MB): staging dead before layer 2 writes bufB
  int* staging = (int*)bufB;

  // edge regroup: dst-group counting sort + per-group src-chunk sort
  hipMemsetAsync(gcount, 0, (size_t)NGROUPS * sizeof(int), stream);
  bin2_kernel<<<(NE + 256 * EPB - 1) / (256 * EPB), 256, 0, stream>>>(src, dst, gcount, staging);
  scan_groups<<<1, 256, 0, stream>>>(gcount, gbase);
  finalize_kernel<<<NGROUPS, 256, 0, stream>>>(staging, gcount, gbase, esrc2);

  // fused conv layers: src-windowed gather -> LDS accumulate -> GEMM -> relu
  conv_g<<<NGROUPS, 256, 0, stream>>>(node_attr, gbase, esrc2, Wc, bc, bufA);
  conv_g<<<NGROUPS, 256, 0, stream>>>(bufA, gbase, esrc2, Wc + 16384, bc + 128, bufB);
  conv_g<<<NGROUPS, 256, 0, stream>>>(bufB, gbase, esrc2, Wc + 32768, bc + 256, bufA);

  // fused pool + head
  pool_head<<<NG, 128, 0, stream>>>(bufA, batching, Wf1, bf1, Wf2, bf2, out);
}

// Round 8
// 1036.143 us; speedup vs baseline: 7.0066x; 7.0066x over previous
//
#include <hip/hip_runtime.h>
#include <math.h>

#define NN 100000
#define NE 3200000
#define NG 1024
#define FDIM 128
#define NFC1 64
#define NFC2 10

#define NGROUPS 1563   // ceil(NN/64) dst groups of 64 nodes
#define CAP2 2432      // per-group staging cap (mean 2048, +8.5 sigma)
#define EPB 16         // edges per thread in bin2_kernel
#define CSHIFT 11      // src chunk = src>>11 (2048 rows = 1 MB fp32)
#define NCH 49         // ceil(100000/2048) src chunks
#define NKEY (8 * NCH) // 392 sort keys: (d>>3)*NCH + chunk

#define RF(x) __builtin_amdgcn_readfirstlane(x)

// ---------------- pass 1: bin edges into 1563 dst-groups ----------------
// Packed value: (dst & 63) << 17 | src   (src < 2^17, dst_local < 2^6)
__global__ __launch_bounds__(256) void bin2_kernel(const int* __restrict__ src,
                                                   const int* __restrict__ dst,
                                                   int* __restrict__ gcount,
                                                   int* __restrict__ staging) {
  __shared__ int hist[NGROUPS];
  __shared__ int base[NGROUPS];
  int t = threadIdx.x;
  for (int i = t; i < NGROUPS; i += 256) hist[i] = 0;
  __syncthreads();
  size_t e0 = (size_t)blockIdx.x * (256 * EPB);
  int bk[EPB], rank[EPB], val[EPB];
#pragma unroll
  for (int j = 0; j < EPB; ++j) {
    size_t e = e0 + (size_t)j * 256 + t;
    if (e < NE) {
      int d = dst[e];
      bk[j] = d >> 6;
      val[j] = ((d & 63) << 17) | src[e];
      rank[j] = atomicAdd(&hist[bk[j]], 1);
    } else {
      bk[j] = -1;
    }
  }
  __syncthreads();
  for (int i = t; i < NGROUPS; i += 256) {
    int h = hist[i];
    base[i] = h > 0 ? atomicAdd(&gcount[i], h) : 0;
  }
  __syncthreads();
#pragma unroll
  for (int j = 0; j < EPB; ++j) {
    if (bk[j] >= 0) {
      int pos = base[bk[j]] + rank[j];
      if (pos < CAP2) staging[(size_t)bk[j] * CAP2 + pos] = val[j];
    }
  }
}

// ---------------- pass 1.5: exclusive scan of group counts ----------------
__global__ __launch_bounds__(256) void scan_groups(const int* __restrict__ gcount,
                                                   int* __restrict__ gbase) {
  __shared__ int s[256];
  __shared__ int carry;
  int t = threadIdx.x;
  if (t == 0) carry = 0;
  __syncthreads();
  for (int tile = 0; tile < (NGROUPS + 255) / 256; ++tile) {
    int i = tile * 256 + t;
    int v = (i < NGROUPS) ? gcount[i] : 0;
    s[t] = v;
    __syncthreads();
    for (int st = 1; st < 256; st <<= 1) {
      int u = (t >= st) ? s[t - st] : 0;
      __syncthreads();
      s[t] += u;
      __syncthreads();
    }
    int c0 = carry;
    if (i < NGROUPS) gbase[i] = c0 + s[t] - v;
    __syncthreads();
    if (t == 255) carry = c0 + s[255];
    __syncthreads();
  }
  if (t == 0) gbase[NGROUPS] = carry;
}

// ---------------- pass 2: per-group sort by (d>>3, src_chunk) ----------------
// Wave w of the conv kernel owns dst rows [8w, 8w+8); sorting by (d>>3) major
// gives each wave a contiguous section; src-chunk minor makes every wave sweep
// src ascending -> all resident blocks gather from a narrow moving src window.
// Also emits woffArr[g*9 + w] = section starts (w=0..8).
__global__ __launch_bounds__(256) void finalize_kernel(const int* __restrict__ staging,
                                                       const int* __restrict__ gcount,
                                                       const int* __restrict__ gbase,
                                                       int* __restrict__ esrc2,
                                                       int* __restrict__ woffArr) {
  __shared__ int vals[CAP2];
  __shared__ int hist[NKEY + 2];
  __shared__ int cur[NKEY];
  __shared__ int s[256];
  __shared__ int carry;
  int g = blockIdx.x, t = threadIdx.x;
  int cnt = gcount[g];
  if (cnt > CAP2) cnt = CAP2;
  int base = gbase[g];
  for (int i = t; i <= NKEY + 1; i += 256) hist[i] = 0;
  if (t == 0) carry = 0;
  __syncthreads();
  const int* sp = staging + (size_t)g * CAP2;
  for (int i = t; i < cnt; i += 256) {
    int v = sp[i];
    vals[i] = v;
    int key = ((v >> 17) >> 3) * NCH + ((v & 0x1FFFF) >> CSHIFT);
    atomicAdd(&hist[key + 1], 1);
  }
  __syncthreads();
  // inclusive scan of hist[0..NKEY] (counts at key+1 -> hist[k] = excl prefix of key k)
  for (int tile = 0; tile * 256 <= NKEY; ++tile) {
    int i = tile * 256 + t;
    int v = (i <= NKEY) ? hist[i] : 0;
    s[t] = v;
    __syncthreads();
    for (int st = 1; st < 256; st <<= 1) {
      int u = (t >= st) ? s[t - st] : 0;
      __syncthreads();
      s[t] += u;
      __syncthreads();
    }
    int c0 = carry;
    if (i <= NKEY) hist[i] = c0 + s[t];
    __syncthreads();
    if (t == 255) carry = c0 + s[255];
    __syncthreads();
  }
  for (int i = t; i < NKEY; i += 256) cur[i] = hist[i];
  __syncthreads();
  for (int i = t; i < cnt; i += 256) {
    int v = vals[i];
    int key = ((v >> 17) >> 3) * NCH + ((v & 0x1FFFF) >> CSHIFT);
    int pos = atomicAdd(&cur[key], 1);
    esrc2[base + pos] = v;
  }
  if (t <= 8) woffArr[g * 9 + t] = hist[t * NCH];  // hist[8*NCH] == cnt
}

// ---------------- fused conv layer: out = relu(gather(x)@W + bias) ----------------
// 512 thr = 8 waves per 64-node group. Wave w owns rows d in [8w,8w+8):
// register accumulators float2 a[8] per lane (features 2*lane, 2*lane+1),
// NO atomics, NO LDS RMW. Edge word is wave-uniform (RF) -> q = d&7 is an
// SGPR -> uniform branch chain dispatches the 2 fma's (scalar pipe, no
// divergence). 8 gathers (float2/lane, 512B/row coalesced) in flight.
// End: 8 ds_write_b64 -> aR -> barrier -> r4's GEMM phase.
__global__ __launch_bounds__(512, 4) void conv_s(const float2* __restrict__ x,
                                                 const int* __restrict__ gbase,
                                                 const int* __restrict__ woffArr,
                                                 const int* __restrict__ esrc2,
                                                 const float* __restrict__ W,
                                                 const float* __restrict__ bias,
                                                 float* __restrict__ out) {
  __shared__ __align__(16) float aR[64 * 132];
  int t = threadIdx.x;
  int w = t >> 6;
  int lane = t & 63;
  int g = blockIdx.x;
  int base = RF(gbase[g]);
  int sbeg = base + RF(woffArr[g * 9 + w]);
  int send = base + RF(woffArr[g * 9 + w + 1]);

  float2 a[8];
#pragma unroll
  for (int j = 0; j < 8; ++j) a[j] = make_float2(0.f, 0.f);

#define ACCUM(VWORD, FV)                                   \
  {                                                        \
    int q_ = ((VWORD) >> 17) & 7;                          \
    switch (q_) {                                          \
      case 0: a[0].x += (FV).x; a[0].y += (FV).y; break;   \
      case 1: a[1].x += (FV).x; a[1].y += (FV).y; break;   \
      case 2: a[2].x += (FV).x; a[2].y += (FV).y; break;   \
      case 3: a[3].x += (FV).x; a[3].y += (FV).y; break;   \
      case 4: a[4].x += (FV).x; a[4].y += (FV).y; break;   \
      case 5: a[5].x += (FV).x; a[5].y += (FV).y; break;   \
      case 6: a[6].x += (FV).x; a[6].y += (FV).y; break;   \
      default: a[7].x += (FV).x; a[7].y += (FV).y; break;  \
    }                                                      \
  }

  int e = sbeg;
  for (; e + 8 <= send; e += 8) {
    int v0 = RF(esrc2[e + 0]);
    int v1 = RF(esrc2[e + 1]);
    int v2 = RF(esrc2[e + 2]);
    int v3 = RF(esrc2[e + 3]);
    int v4 = RF(esrc2[e + 4]);
    int v5 = RF(esrc2[e + 5]);
    int v6 = RF(esrc2[e + 6]);
    int v7 = RF(esrc2[e + 7]);
    float2 f0 = x[(size_t)(v0 & 0x1FFFF) * 64 + lane];
    float2 f1 = x[(size_t)(v1 & 0x1FFFF) * 64 + lane];
    float2 f2 = x[(size_t)(v2 & 0x1FFFF) * 64 + lane];
    float2 f3 = x[(size_t)(v3 & 0x1FFFF) * 64 + lane];
    float2 f4 = x[(size_t)(v4 & 0x1FFFF) * 64 + lane];
    float2 f5 = x[(size_t)(v5 & 0x1FFFF) * 64 + lane];
    float2 f6 = x[(size_t)(v6 & 0x1FFFF) * 64 + lane];
    float2 f7 = x[(size_t)(v7 & 0x1FFFF) * 64 + lane];
    ACCUM(v0, f0); ACCUM(v1, f1); ACCUM(v2, f2); ACCUM(v3, f3);
    ACCUM(v4, f4); ACCUM(v5, f5); ACCUM(v6, f6); ACCUM(v7, f7);
  }
  for (; e < send; ++e) {
    int v0 = RF(esrc2[e]);
    float2 f0 = x[(size_t)(v0 & 0x1FFFF) * 64 + lane];
    ACCUM(v0, f0);
  }
#undef ACCUM

#pragma unroll
  for (int j = 0; j < 8; ++j) {
    *(float2*)&aR[(w * 8 + j) * 132 + 2 * lane] = a[j];
  }
  __syncthreads();

  // ---- GEMM 64x128 tile (r4 structure) ----
  int rg = lane >> 5;
  int c = lane & 31;
  int rbase = w * 8 + rg * 4;

  float s4[4][4];
#pragma unroll
  for (int r = 0; r < 4; ++r)
#pragma unroll
    for (int j = 0; j < 4; ++j) s4[r][j] = 0.f;

#pragma unroll 2
  for (int k = 0; k < 128; k += 4) {
    float4 b0 = *(const float4*)(W + (k + 0) * FDIM + c * 4);
    float4 b1 = *(const float4*)(W + (k + 1) * FDIM + c * 4);
    float4 b2 = *(const float4*)(W + (k + 2) * FDIM + c * 4);
    float4 b3 = *(const float4*)(W + (k + 3) * FDIM + c * 4);
    float4 av[4];
    av[0] = *(const float4*)&aR[(rbase + 0) * 132 + k];
    av[1] = *(const float4*)&aR[(rbase + 1) * 132 + k];
    av[2] = *(const float4*)&aR[(rbase + 2) * 132 + k];
    av[3] = *(const float4*)&aR[(rbase + 3) * 132 + k];
#pragma unroll
    for (int r = 0; r < 4; ++r) {
      s4[r][0] += av[r].x * b0.x + av[r].y * b1.x + av[r].z * b2.x + av[r].w * b3.x;
      s4[r][1] += av[r].x * b0.y + av[r].y * b1.y + av[r].z * b2.y + av[r].w * b3.y;
      s4[r][2] += av[r].x * b0.z + av[r].y * b1.z + av[r].z * b2.z + av[r].w * b3.z;
      s4[r][3] += av[r].x * b0.w + av[r].y * b1.w + av[r].z * b2.w + av[r].w * b3.w;
    }
  }

  float4 bb = *(const float4*)(bias + c * 4);
#pragma unroll
  for (int r = 0; r < 4; ++r) {
    int row = g * 64 + rbase + r;
    if (row < NN) {
      float4 o;
      o.x = fmaxf(s4[r][0] + bb.x, 0.f);
      o.y = fmaxf(s4[r][1] + bb.y, 0.f);
      o.z = fmaxf(s4[r][2] + bb.z, 0.f);
      o.w = fmaxf(s4[r][3] + bb.w, 0.f);
      *(float4*)(out + (size_t)row * FDIM + c * 4) = o;
    }
  }
}

// ---------------- fused global pool + FC1 + FC2 + softmax ----------------
__device__ int lower_bound_dev(const int* __restrict__ arr, int n, int val) {
  int lo = 0, hi = n;
  while (lo < hi) {
    int mid = (lo + hi) >> 1;
    if (arr[mid] < val) lo = mid + 1; else hi = mid;
  }
  return lo;
}

__global__ __launch_bounds__(128) void pool_head(const float* __restrict__ x,
                                                 const int* __restrict__ batching,
                                                 const float* __restrict__ Wf1,
                                                 const float* __restrict__ bf1,
                                                 const float* __restrict__ Wf2,
                                                 const float* __restrict__ bf2,
                                                 float* __restrict__ out) {
  __shared__ int se, ee;
  __shared__ float gl[128];
  __shared__ float hl[64];
  __shared__ float ol[10];
  __shared__ float red[2];
  int gid = blockIdx.x, t = threadIdx.x;
  if (t == 0) {
    se = lower_bound_dev(batching, NN, gid);
    ee = lower_bound_dev(batching, NN, gid + 1);
  }
  __syncthreads();
  float acc = 0.f;
  for (int n = se; n < ee; ++n) acc += x[(size_t)n * FDIM + t];
  gl[t] = acc;
  __syncthreads();
  if (t < NFC1) {
    float h = bf1[t];
    for (int f = 0; f < 128; ++f) h += gl[f] * Wf1[f * NFC1 + t];
    hl[t] = h;
  }
  __syncthreads();
  if (t < NFC2) {
    float o = bf2[t];
    for (int i = 0; i < NFC1; ++i) o += hl[i] * Wf2[i * NFC2 + t];
    ol[t] = o;
  }
  __syncthreads();
  if (t == 0) {
    float m = ol[0];
    for (int i = 1; i < NFC2; ++i) m = fmaxf(m, ol[i]);
    float sum = 0.f;
    for (int i = 0; i < NFC2; ++i) sum += expf(ol[i] - m);
    red[0] = m;
    red[1] = sum;
  }
  __syncthreads();
  if (t < NFC2) out[(size_t)gid * NFC2 + t] = expf(ol[t] - red[0]) / red[1];
}

extern "C" void kernel_launch(void* const* d_in, const int* in_sizes, int n_in,
                              void* d_out, int out_size, void* d_ws, size_t ws_size,
                              hipStream_t stream) {
  const float* node_attr = (const float*)d_in[0];
  const float* Wc = (const float*)d_in[1];   // [3][128][128]
  const float* bc = (const float*)d_in[2];   // [3][128]
  const float* Wf1 = (const float*)d_in[3];  // [128][64]
  const float* bf1 = (const float*)d_in[4];
  const float* Wf2 = (const float*)d_in[5];  // [64][10]
  const float* bf2 = (const float*)d_in[6];
  const int* src = (const int*)d_in[7];
  const int* dst = (const int*)d_in[8];
  const int* batching = (const int*)d_in[9];
  float* out = (float*)d_out;

  char* wsp = (char*)d_ws;
  size_t off = 0;
  auto alloc = [&](size_t bytes) -> void* {
    void* p = wsp + off;
    off += (bytes + 255) & ~(size_t)255;
    return p;
  };
  int* gcount = (int*)alloc((size_t)NGROUPS * sizeof(int));
  int* gbase = (int*)alloc((size_t)(NGROUPS + 1) * sizeof(int));
  int* woffArr = (int*)alloc((size_t)NGROUPS * 9 * sizeof(int));
  int* esrc2 = (int*)alloc((size_t)NE * sizeof(int));
  float* bufA = (float*)alloc((size_t)NN * FDIM * sizeof(float));
  float* bufB = (float*)alloc((size_t)NN * FDIM * sizeof(float));
  // staging (15.2 MB) aliases bufB (51.2 MB): staging dead before layer 2 writes bufB
  int* staging = (int*)bufB;

  // edge regroup: dst-group counting sort + per-group (d>>3, src-chunk) sort
  hipMemsetAsync(gcount, 0, (size_t)NGROUPS * sizeof(int), stream);
  bin2_kernel<<<(NE + 256 * EPB - 1) / (256 * EPB), 256, 0, stream>>>(src, dst, gcount, staging);
  scan_groups<<<1, 256, 0, stream>>>(gcount, gbase);
  finalize_kernel<<<NGROUPS, 256, 0, stream>>>(staging, gcount, gbase, esrc2, woffArr);

  // fused conv layers: src-windowed register-accumulated gather -> GEMM -> relu
  conv_s<<<NGROUPS, 512, 0, stream>>>((const float2*)node_attr, gbase, woffArr, esrc2,
                                      Wc, bc, bufA);
  conv_s<<<NGROUPS, 512, 0, stream>>>((const float2*)bufA, gbase, woffArr, esrc2,
                                      Wc + 16384, bc + 128, bufB);
  conv_s<<<NGROUPS, 512, 0, stream>>>((const float2*)bufB, gbase, woffArr, esrc2,
                                      Wc + 32768, bc + 256, bufA);

  // fused pool + head
  pool_head<<<NG, 128, 0, stream>>>(bufA, batching, Wf1, bf1, Wf2, bf2, out);
}